// Round 9
// baseline (127112.537 us; speedup 1.0000x reference)
//
#include <hip/hip_runtime.h>

#define HH 128      // hidden size
#define G4 512      // 4*HH gates
#define TT 102400   // sequence length
#define BB 8        // batch
#define HS 144      // LDS halfs per batch (128 + 16 pad)
#define HB4 (4 * HS)   // 576 halfs per buffer (4 batches/block)

typedef _Float16 v2h __attribute__((ext_vector_type(2)));
typedef _Float16 v8h __attribute__((ext_vector_type(8)));
typedef float f32x4 __attribute__((ext_vector_type(4)));

#define MFMA16(a, b, c) __builtin_amdgcn_mfma_f32_16x16x32_f16((a), (b), (c), 0, 0, 0)

#if __has_builtin(__builtin_amdgcn_fdot2)
#define FDOT2(a, b, c) __builtin_amdgcn_fdot2((a), (b), (c), false)
#else
static __device__ __forceinline__ float fdot2_fb(v2h a, v2h b, float c) {
    return fmaf((float)a[0], (float)b[0], fmaf((float)a[1], (float)b[1], c));
}
#define FDOT2(a, b, c) fdot2_fb((a), (b), (c))
#endif

template<int CTRL>
__device__ __forceinline__ float dpp_mov(float v) {
    return __int_as_float(
        __builtin_amdgcn_update_dpp(0, __float_as_int(v), CTRL, 0xF, 0xF, true));
}

__device__ __forceinline__ float sig_f(float x) {
    return __builtin_amdgcn_rcpf(1.0f + __expf(-x));
}
__device__ __forceinline__ float tanh_f(float x) {
    return fmaf(2.0f, __builtin_amdgcn_rcpf(1.0f + __expf(-2.0f * x)), -1.0f);
}
// dynamic element-select from f32x4 (2-level cndmask tree)
__device__ __forceinline__ float sel4(f32x4 v, int d) {
    float e01 = (d & 1) ? v[1] : v[0];
    float e23 = (d & 1) ? v[3] : v[2];
    return (d & 2) ? e23 : e01;
}

union HI { int i; v2h h; };

// ---------------- stage-B helpers (R7, verified) ---------------------------
__device__ __forceinline__ float dotred(const v2h w[8][8],
                                        const _Float16* __restrict__ hsl,
                                        bool bp1, bool bp2, bool bp3) {
    const int4* hp4 = (const int4*)hsl;
    int4 ha = hp4[0], hb = hp4[1];
    int hp[8] = {ha.x, ha.y, ha.z, ha.w, hb.x, hb.y, hb.z, hb.w};
    float acc[8];
#pragma unroll
    for (int r = 0; r < 8; ++r) acc[r] = 0.f;
#pragma unroll
    for (int i = 0; i < 8; ++i) {
        HI u; u.i = hp[i];
#pragma unroll
        for (int r = 0; r < 8; ++r) acc[r] = FDOT2(w[r][i], u.h, acc[r]);
    }
    float b0[4];
#pragma unroll
    for (int m = 0; m < 4; ++m) {
        float send = bp1 ? acc[2 * m] : acc[2 * m + 1];
        float keep = bp1 ? acc[2 * m + 1] : acc[2 * m];
        b0[m] = keep + dpp_mov<0xB1>(send);
    }
    float d0[2];
#pragma unroll
    for (int i = 0; i < 2; ++i) {
        float send = bp2 ? b0[i] : b0[i + 2];
        float keep = bp2 ? b0[i + 2] : b0[i];
        d0[i] = keep + dpp_mov<0x4E>(send);
    }
    float send = bp3 ? d0[0] : d0[1];
    float keep = bp3 ? d0[1] : d0[0];
    return keep + dpp_mov<0x141>(send);
}

__device__ __forceinline__ void load_w8h(const float* __restrict__ W,
                                         int Q, int j, v2h w[8][8]) {
#pragma unroll
    for (int r = 0; r < 8; ++r) {
        int row = 2 * Q + (r & 1) + 128 * (r >> 1);
        const float4* rp = (const float4*)(W + (size_t)row * HH + 16 * j);
#pragma unroll
        for (int i = 0; i < 4; ++i) {
            float4 f = rp[i];
            w[r][2 * i]     = (v2h){(_Float16)f.x, (_Float16)f.y};
            w[r][2 * i + 1] = (v2h){(_Float16)f.z, (_Float16)f.w};
        }
    }
}

// ---------------------------------------------------------------------------
// One pipeline slot (512 threads/block):
//   blocks 0,1 = stage A (layer0 chain, chunk c):  batches 0-3 / 4-7, MFMA
//   blocks 2,3 = stage C (layer1 chain, chunk c-2): batches 0-3 / 4-7, MFMA
//   blocks 4..67 = stage B (xp1 GEMM, chunk c-1), R7 VALU path
// Chain blocks use 4 worker waves (1/SIMD); waves 4-7 spin matching barriers.
// MFMA layouts (R8-verified): A[m=lane&15][k=quad*8+j], B[k=quad*8+j][n],
// D[m=quad*4+r][n=lane&15]. N: batch = n16&3 (4-way dup); dup id d=n16>>2
// picks D row r=d, so each lane's epilogue = 1 cell per m-tile, 1 batch.
// ---------------------------------------------------------------------------
__global__ void __launch_bounds__(512, 2)
lstm_slot_kernel(
    const float* __restrict__ x,
    const float* __restrict__ Wih0, const float* __restrict__ Whh0,
    const float* __restrict__ bih0, const float* __restrict__ bhh0,
    const float* __restrict__ Wih1, const float* __restrict__ Whh1,
    const float* __restrict__ bih1, const float* __restrict__ bhh1,
    float* __restrict__ h1s, float* __restrict__ c1s,
    float* __restrict__ h2s, float* __restrict__ c2s,
    double* __restrict__ pooled,
    _Float16* __restrict__ h1ring,  // [2][B][chunkT][HH] fp16
    float* __restrict__ xpring,     // [2][B][chunkT][HH][4] (t,cell,gate) f32
    int c, int chunkT, int nchunks)
{
    __shared__ __align__(16) _Float16 hsh[2 * HB4];   // 2304 B
    const int t = threadIdx.x;

    if (blockIdx.x < 4) {
        // =============== MFMA chain stages ===============
        const bool isA = (blockIdx.x < 2);
        const int bbase = (blockIdx.x & 1) * 4;        // batches 0-3 or 4-7
        const int cc = isA ? c : (c - 2);
        if (cc < 0 || cc >= nchunks) return;
        const int nt4 = chunkT >> 2;
        if (t >= 256) {   // idle waves: match worker barrier count exactly
            __syncthreads();
            for (int i = 0; i < nt4 * 4; ++i) __syncthreads();
            return;
        }
        const int lane = t & 63, wv = t >> 6;          // wv 0..3
        const int quad = lane >> 4, n16 = lane & 15;
        const int nb = n16 & 3, dsel = n16 >> 2;
        const int b = bbase + nb;
        const int cellA = 32 * wv + 4 * quad + dsel;
        const int cellB = cellA + 16;

        // ---- A-frags fp32->fp16 (once per slot); may live in AGPRs (fine) --
        v8h a[2][4][4];
        const float* Wl = isA ? Whh0 : Whh1;
#pragma unroll
        for (int mt = 0; mt < 2; ++mt)
#pragma unroll
            for (int g = 0; g < 4; ++g)
#pragma unroll
                for (int kt = 0; kt < 4; ++kt) {
                    const float* rp = Wl
                        + (size_t)(32 * wv + 16 * mt + n16 + 128 * g) * HH
                        + 32 * kt + 8 * quad;
                    v8h av;
#pragma unroll
                    for (int e = 0; e < 8; ++e) av[e] = (_Float16)rp[e];
                    a[mt][g][kt] = av;
                }
        f32x4 biasf[2][4];
        float wih[2][4];
#pragma unroll
        for (int mt = 0; mt < 2; ++mt)
#pragma unroll
            for (int g = 0; g < 4; ++g) {
                f32x4 bv = {0.f, 0.f, 0.f, 0.f};
                if (isA) {
#pragma unroll
                    for (int r = 0; r < 4; ++r) {
                        int row = 32 * wv + 16 * mt + 4 * quad + r + 128 * g;
                        bv[r] = bih0[row] + bhh0[row];
                    }
                    wih[mt][g] = Wih0[(mt ? cellB : cellA) + 128 * g];
                } else {
                    wih[mt][g] = 0.f;
                }
                biasf[mt][g] = bv;
            }

        float* cst = isA ? c1s : c2s;
        float* hst = isA ? h1s : h2s;
        float crA = cst[b * HH + cellA], crB = cst[b * HH + cellB];
        hsh[nb * HS + cellA] = (_Float16)hst[b * HH + cellA];
        hsh[nb * HS + cellB] = (_Float16)hst[b * HH + cellB];

        _Float16* ringp = h1ring
            + ((size_t)((c & 1) * BB + b)) * (size_t)chunkT * HH;
        const float* xps = xpring
            + ((size_t)((cc & 1) * BB + b)) * (size_t)chunkT * G4;
        const float4* xb4 = (const float4*)(x + (size_t)b * TT + (size_t)cc * chunkT);

        float4 xcur = {0, 0, 0, 0}, xnxt = {0, 0, 0, 0};
        f32x4 xpA[4], xpB[4];
        if (isA) {
            xcur = xb4[0];
        } else {
#pragma unroll
            for (int u = 0; u < 4; ++u) {
                const float* p = xps + (size_t)u * G4;
                xpA[u] = *(const f32x4*)(p + 4 * cellA);
                xpB[u] = *(const f32x4*)(p + 4 * cellB);
            }
        }
        float hAo = 0.f, hBo = 0.f;
        double paA = 0.0, paB = 0.0;
        __syncthreads();

        for (int t4 = 0; t4 < nt4; ++t4) {
            if (isA) xnxt = (t4 + 1 < nt4) ? xb4[t4 + 1] : xcur;
#pragma unroll
            for (int u = 0; u < 4; ++u) {
                const int buf = u & 1;
                const _Float16* hb = hsh + buf * HB4 + nb * HS + 8 * quad;
                v8h bf0 = *(const v8h*)(hb);
                v8h bf1 = *(const v8h*)(hb + 32);
                v8h bf2 = *(const v8h*)(hb + 64);
                v8h bf3 = *(const v8h*)(hb + 96);
                f32x4 dd[2][4];
#pragma unroll
                for (int mt = 0; mt < 2; ++mt)
#pragma unroll
                    for (int g = 0; g < 4; ++g) dd[mt][g] = biasf[mt][g];
#pragma unroll
                for (int g = 0; g < 4; ++g) {
                    dd[0][g] = MFMA16(a[0][g][0], bf0, dd[0][g]);
                    dd[1][g] = MFMA16(a[1][g][0], bf0, dd[1][g]);
                    dd[0][g] = MFMA16(a[0][g][1], bf1, dd[0][g]);
                    dd[1][g] = MFMA16(a[1][g][1], bf1, dd[1][g]);
                    dd[0][g] = MFMA16(a[0][g][2], bf2, dd[0][g]);
                    dd[1][g] = MFMA16(a[1][g][2], bf2, dd[1][g]);
                    dd[0][g] = MFMA16(a[0][g][3], bf3, dd[0][g]);
                    dd[1][g] = MFMA16(a[1][g][3], bf3, dd[1][g]);
                }
                float preA[4], preB[4];
#pragma unroll
                for (int g = 0; g < 4; ++g) {
                    preA[g] = sel4(dd[0][g], dsel);
                    preB[g] = sel4(dd[1][g], dsel);
                }
                if (isA) {
                    float xt = (u == 0) ? xcur.x : (u == 1) ? xcur.y
                             : (u == 2) ? xcur.z : xcur.w;
#pragma unroll
                    for (int g = 0; g < 4; ++g) {
                        preA[g] = fmaf(xt, wih[0][g], preA[g]);
                        preB[g] = fmaf(xt, wih[1][g], preB[g]);
                    }
                } else {
#pragma unroll
                    for (int g = 0; g < 4; ++g) {
                        preA[g] += xpA[u][g];
                        preB[g] += xpB[u][g];
                    }
                    int s = t4 * 4 + u + 4;        // refill: 4 steps ahead
                    if (s < chunkT) {
                        const float* p = xps + (size_t)s * G4;
                        xpA[u] = *(const f32x4*)(p + 4 * cellA);
                        xpB[u] = *(const f32x4*)(p + 4 * cellB);
                    }
                }
                float iA = sig_f(preA[0]), fA = sig_f(preA[1]);
                float gA = tanh_f(preA[2]), oA = sig_f(preA[3]);
                float iB = sig_f(preB[0]), fB = sig_f(preB[1]);
                float gB = tanh_f(preB[2]), oB = sig_f(preB[3]);
                crA = fmaf(fA, crA, iA * gA);
                crB = fmaf(fB, crB, iB * gB);
                float hA = oA * tanh_f(crA);
                float hB = oB * tanh_f(crB);
                hsh[(buf ^ 1) * HB4 + nb * HS + cellA] = (_Float16)hA;
                hsh[(buf ^ 1) * HB4 + nb * HS + cellB] = (_Float16)hB;
                if (isA) {
                    ringp[(size_t)(t4 * 4 + u) * HH + cellA] = (_Float16)hA;
                    ringp[(size_t)(t4 * 4 + u) * HH + cellB] = (_Float16)hB;
                } else {
                    paA += (double)hA;
                    paB += (double)hB;
                }
                hAo = hA; hBo = hB;
                __syncthreads();
            }
            xcur = xnxt;
        }
        cst[b * HH + cellA] = crA;
        cst[b * HH + cellB] = crB;
        hst[b * HH + cellA] = hAo;
        hst[b * HH + cellB] = hBo;
        if (!isA) {
            pooled[b * HH + cellA] += paA;
            pooled[b * HH + cellB] += paB;
        }

    } else {
        // ---------------- stage B: xp1 = Wih1 @ h1 + bias, chunk c-1 -------
        const int bc = c - 1;
        if (bc < 0 || bc >= nchunks) return;
        const int ib = blockIdx.x - 4;        // 0..63
        const int bb = ib >> 3;               // batch
        const int sl = ib & 7;                // t-slice (stride 8)
        const int Q = t >> 3, j = t & 7;
        const bool bp1 = ((j ^ (j >> 2)) & 1) != 0;
        const bool bp2 = ((j ^ (j >> 1)) & 1) != 0;
        const bool bp3 = ((j >> 2) & 1) != 0;
        const int cellj = bp1 ? 1 : 0;
        const int gatej = (bp2 ? 2 : 0) + (bp3 ? 1 : 0);
        const int myc = 2 * Q + cellj;
        const int myrow = myc + 128 * gatej;
        v2h w[8][8];
        load_w8h(Wih1, Q, j, w);
        const float bias_l = bih1[myrow] + bhh1[myrow];
        const _Float16* hrp = h1ring
            + ((size_t)((bc & 1) * BB + bb)) * (size_t)chunkT * HH;
        float* xpw = xpring + ((size_t)((bc & 1) * BB + bb)) * (size_t)chunkT * G4;
        if (t < HH) hsh[t] = hrp[(size_t)sl * HH + t];
        __syncthreads();
        int pb = 0;
        for (int tt = sl; tt < chunkT; tt += 8) {
            int ttn = tt + 8;
            bool pf = (t < HH) && (ttn < chunkT);
            _Float16 hn = (_Float16)0.f;
            if (pf) hn = hrp[(size_t)ttn * HH + t];
            float sfin = dotred(w, hsh + pb * HH + 16 * j, bp1, bp2, bp3);
            if (pf) hsh[(pb ^ 1) * HH + t] = hn;
            xpw[(size_t)tt * G4 + 4 * myc + gatej] = sfin + bias_l;
            __syncthreads();
            pb ^= 1;
        }
    }
}

// ---------------- head: mean-pool (done) -> FC+ReLU -> FC ------------------
__global__ void head_kernel(const double* __restrict__ pooled,
                            const float* __restrict__ fcW1, const float* __restrict__ fcb1,
                            const float* __restrict__ fcW2, const float* __restrict__ fcb2,
                            float* __restrict__ out)
{
    __shared__ float p_s[HH];
    __shared__ float hid_s[64];
    const int b = blockIdx.x, t = threadIdx.x;
    if (t < HH) p_s[t] = (float)(pooled[b * HH + t] * (1.0 / (double)TT));
    __syncthreads();
    if (t < 64) {
        float acc = fcb1[t];
#pragma unroll 8
        for (int k = 0; k < HH; ++k) acc = fmaf(p_s[k], fcW1[t * HH + k], acc);
        hid_s[t] = fmaxf(acc, 0.f);
    }
    __syncthreads();
    if (t < 11) {
        float acc = fcb2[t];
#pragma unroll
        for (int k = 0; k < 64; ++k) acc = fmaf(hid_s[k], fcW2[t * 64 + k], acc);
        out[b * 11 + t] = acc;
    }
}

// ---------------------------------------------------------------------------
extern "C" void kernel_launch(void* const* d_in, const int* in_sizes, int n_in,
                              void* d_out, int out_size, void* d_ws, size_t ws_size,
                              hipStream_t stream)
{
    const float* x    = (const float*)d_in[0];
    const float* Wih0 = (const float*)d_in[1];
    const float* Whh0 = (const float*)d_in[2];
    const float* bih0 = (const float*)d_in[3];
    const float* bhh0 = (const float*)d_in[4];
    const float* Wih1 = (const float*)d_in[5];
    const float* Whh1 = (const float*)d_in[6];
    const float* bih1 = (const float*)d_in[7];
    const float* bhh1 = (const float*)d_in[8];
    const float* fcW1 = (const float*)d_in[9];
    const float* fcb1 = (const float*)d_in[10];
    const float* fcW2 = (const float*)d_in[11];
    const float* fcb2 = (const float*)d_in[12];
    float* out = (float*)d_out;

    // ---- workspace layout ----
    char* wsp = (char*)d_ws;
    float*  h1s    = (float*) (wsp + 0);
    float*  c1s    = (float*) (wsp + 4096);
    float*  h2s    = (float*) (wsp + 8192);
    float*  c2s    = (float*) (wsp + 12288);
    double* pooled = (double*)(wsp + 16384);          // 8 KB
    const size_t STATE_BYTES = 24576;

    // per-t ring bytes: h1 fp16 2*8*128*2 = 4096 ; xp fp32 2*8*512*4 = 32768
    static const int cands[] = {3200, 1600, 800, 400, 160, 80, 40, 8};
    int chunkT = 8;
    for (int i = 0; i < 8; ++i) {
        size_t need = STATE_BYTES + (size_t)36864 * (size_t)cands[i];
        if (need <= ws_size) { chunkT = cands[i]; break; }
    }
    const int nchunks = TT / chunkT;

    _Float16* h1ring = (_Float16*)(wsp + STATE_BYTES);
    float* xpring = (float*)(wsp + STATE_BYTES + (size_t)2 * BB * chunkT * HH * 2);

    // zero persistent state (h/c/pooled); ws is re-poisoned before every call
    hipMemsetAsync(d_ws, 0, STATE_BYTES, stream);

    // pipeline: slot c runs A(c) || B(c-1) || C(c-2)
    const int nslots = nchunks + 2;
    for (int c = 0; c < nslots; ++c) {
        lstm_slot_kernel<<<68, 512, 0, stream>>>(
            x, Wih0, Whh0, bih0, bhh0, Wih1, Whh1, bih1, bhh1,
            h1s, c1s, h2s, c2s, pooled, h1ring, xpring,
            c, chunkT, nchunks);
    }
    head_kernel<<<BB, 128, 0, stream>>>(pooled, fcW1, fcb1, fcW2, fcb2, out);
}

// Round 10
// 115268.042 us; speedup vs baseline: 1.1028x; 1.1028x over previous
//
#include <hip/hip_runtime.h>

#define HH 128      // hidden size
#define G4 512      // 4*HH gates
#define TT 102400   // sequence length
#define BB 8        // batch

typedef _Float16 v2h __attribute__((ext_vector_type(2)));

#if __has_builtin(__builtin_amdgcn_fdot2)
#define FDOT2(a, b, c) __builtin_amdgcn_fdot2((a), (b), (c), false)
#else
static __device__ __forceinline__ float fdot2_fb(v2h a, v2h b, float c) {
    return fmaf((float)a[0], (float)b[0], fmaf((float)a[1], (float)b[1], c));
}
#define FDOT2(a, b, c) fdot2_fb((a), (b), (c))
#endif

// DPP lane move (VALU pipe): 0xB1=xor1(quad), 0x4E=xor2(quad), 0x141=xor7
template<int CTRL>
__device__ __forceinline__ float dpp_mov(float v) {
    return __int_as_float(
        __builtin_amdgcn_update_dpp(0, __float_as_int(v), CTRL, 0xF, 0xF, true));
}

__device__ __forceinline__ float tanh_f(float x) {
    return fmaf(2.0f, __builtin_amdgcn_rcpf(1.0f + __expf(-2.0f * x)), -1.0f);
}

union HI { int i; v2h h; };

// ---------------------------------------------------------------------------
// R7-verified reduce-to-distinct: lane j of each 8-lane group covers
// k in [16j,16j+16) of 8 gate rows; after 3 DPP rounds lane j holds the FULL
// 128-dot of row (cell=j0^j2, gate=2*(j0^j1)+j2).
// ---------------------------------------------------------------------------
__device__ __forceinline__ float dotred(const v2h w[8][8],
                                        const _Float16* __restrict__ hsl,
                                        bool bp1, bool bp2, bool bp3) {
    const int4* hp4 = (const int4*)hsl;     // 2x ds_read_b128 (16 halfs)
    int4 ha = hp4[0], hb = hp4[1];
    int hp[8] = {ha.x, ha.y, ha.z, ha.w, hb.x, hb.y, hb.z, hb.w};
    float acc[8];
#pragma unroll
    for (int r = 0; r < 8; ++r) acc[r] = 0.f;
#pragma unroll
    for (int i = 0; i < 8; ++i) {
        HI u; u.i = hp[i];
#pragma unroll
        for (int r = 0; r < 8; ++r) acc[r] = FDOT2(w[r][i], u.h, acc[r]);
    }
    float b0[4];
#pragma unroll
    for (int m = 0; m < 4; ++m) {
        float send = bp1 ? acc[2 * m] : acc[2 * m + 1];
        float keep = bp1 ? acc[2 * m + 1] : acc[2 * m];
        b0[m] = keep + dpp_mov<0xB1>(send);
    }
    float d0[2];
#pragma unroll
    for (int i = 0; i < 2; ++i) {
        float send = bp2 ? b0[i] : b0[i + 2];
        float keep = bp2 ? b0[i + 2] : b0[i];
        d0[i] = keep + dpp_mov<0x4E>(send);
    }
    float send = bp3 ? d0[0] : d0[1];
    float keep = bp3 ? d0[1] : d0[0];
    return keep + dpp_mov<0x141>(send);
}

// load this lane's fp16 weight slices: rows rho=0..7 -> W row 2Q+(rho&1)+128*(rho>>1)
__device__ __forceinline__ void load_w8h(const float* __restrict__ W,
                                         int Q, int j, v2h w[8][8]) {
#pragma unroll
    for (int r = 0; r < 8; ++r) {
        int row = 2 * Q + (r & 1) + 128 * (r >> 1);
        const float4* rp = (const float4*)(W + (size_t)row * HH + 16 * j);
#pragma unroll
        for (int i = 0; i < 4; ++i) {
            float4 f = rp[i];
            w[r][2 * i]     = (v2h){(_Float16)f.x, (_Float16)f.y};
            w[r][2 * i + 1] = (v2h){(_Float16)f.z, (_Float16)f.w};
        }
    }
}

// ---------------------------------------------------------------------------
// One pipeline slot (512 threads/block):
//   blocks 0..3  = stage A (layer0 chain, chunk c), batch pair {b, b+4}
//   blocks 4..7  = stage C (layer1 chain, chunk c-2), batch pair {b, b+4}
//   blocks 8..71 = stage B (xp1 GEMM, chunk c-1): 8 batch x 8 t-slice
// Pairing rationale: weights are batch-invariant (shared w regs); the second
// chain's independent dependency chain interleaves with the first's, hiding
// the ~900-cyc serial stall R7 exposed. Stream order gives producer->consumer
// ordering across launches.
// ---------------------------------------------------------------------------
__global__ void __launch_bounds__(512, 2)
lstm_slot_kernel(
    const float* __restrict__ x,
    const float* __restrict__ Wih0, const float* __restrict__ Whh0,
    const float* __restrict__ bih0, const float* __restrict__ bhh0,
    const float* __restrict__ Wih1, const float* __restrict__ Whh1,
    const float* __restrict__ bih1, const float* __restrict__ bhh1,
    float* __restrict__ h1s, float* __restrict__ c1s,
    float* __restrict__ h2s, float* __restrict__ c2s,
    double* __restrict__ pooled,
    _Float16* __restrict__ h1ring,  // [2][B][chunkT][HH]   fp16
    float* __restrict__ xpring,     // [2][B][chunkT][HH][4] (t,cell,gate) f32
    int c, int chunkT, int nchunks)
{
    // chains: [buf][bat][HH] = 2*2*128 halfs; stage B uses first 256 halfs
    __shared__ __align__(32) _Float16 hh[512];
    const int t = threadIdx.x;
    const int Q = t >> 3;                 // 8-lane group -> cells {2Q, 2Q+1}
    const int j = t & 7;
    const bool bp1 = ((j ^ (j >> 2)) & 1) != 0;   // phi1 = j0^j2 (cell bit)
    const bool bp2 = ((j ^ (j >> 1)) & 1) != 0;   // phi2 = j0^j1 (gate hi)
    const bool bp3 = ((j >> 2) & 1) != 0;         // phi3 = j2    (gate lo)
    const int cellj = bp1 ? 1 : 0;
    const int gatej = (bp2 ? 2 : 0) + (bp3 ? 1 : 0);
    const int myc   = 2 * Q + cellj;
    const int myrow = myc + 128 * gatej;
    const bool owner = (gatej == 0);              // gate-i lanes: j in {0,3}
    const bool isg = (gatej == 2);
    const float fe = isg ? -2.f : -1.f;
    const float fm = isg ?  2.f :  1.f;
    const float fa = isg ? -1.f :  0.f;

    if (blockIdx.x < 8) {
        // ====== chain stages (A: layer0, C: layer1), 2 batches/block ======
        const bool isA = (blockIdx.x < 4);
        const int cc = isA ? c : (c - 2);
        if (cc < 0 || cc >= nchunks) return;
        const int b0 = blockIdx.x & 3;        // batches b0 and b0+4
        const int b1 = b0 + 4;

        v2h w[8][8];                          // shared by both batches!
        load_w8h(isA ? Whh0 : Whh1, Q, j, w);
        float bias_l = 0.f, wih_l = 0.f;
        if (isA) { bias_l = bih0[myrow] + bhh0[myrow]; wih_l = Wih0[myrow]; }

        float* hst = isA ? h1s : h2s;
        float* cst = isA ? c1s : c2s;
        float cr0 = cst[b0 * HH + myc];
        float cr1 = cst[b1 * HH + myc];
        if (t < HH) {
            hh[t]       = (_Float16)hst[b0 * HH + t];
            hh[HH + t]  = (_Float16)hst[b1 * HH + t];
        }

        _Float16* ring0 = h1ring + ((size_t)((c & 1) * BB + b0)) * (size_t)chunkT * HH;
        _Float16* ring1 = h1ring + ((size_t)((c & 1) * BB + b1)) * (size_t)chunkT * HH;
        const float4* xb0 = (const float4*)(x + (size_t)b0 * TT + (size_t)cc * chunkT);
        const float4* xb1 = (const float4*)(x + (size_t)b1 * TT + (size_t)cc * chunkT);
        const float* xps0 = xpring
            + ((size_t)((cc & 1) * BB + b0)) * (size_t)chunkT * G4 + 4 * myc + gatej;
        const float* xps1 = xpring
            + ((size_t)((cc & 1) * BB + b1)) * (size_t)chunkT * G4 + 4 * myc + gatej;

        const int nt4 = chunkT >> 2;
        float4 xq0 = {0, 0, 0, 0}, xq1 = {0, 0, 0, 0};
        float xpc0[4] = {0, 0, 0, 0}, xpc1[4] = {0, 0, 0, 0};
        if (isA) {
            xq0 = xb0[0]; xq1 = xb1[0];
        } else {
#pragma unroll
            for (int u = 0; u < 4; ++u) {
                xpc0[u] = xps0[(size_t)u * G4];
                xpc1[u] = xps1[(size_t)u * G4];
            }
        }
        double pa0 = 0.0, pa1 = 0.0;
        float hf0 = 0.f, hf1 = 0.f;
        __syncthreads();

        for (int t4 = 0; t4 < nt4; ++t4) {
            float4 xn0 = {0, 0, 0, 0}, xn1 = {0, 0, 0, 0};
            float xpn0[4] = {0, 0, 0, 0}, xpn1[4] = {0, 0, 0, 0};
            if (isA) {
                if (t4 + 1 < nt4) { xn0 = xb0[t4 + 1]; xn1 = xb1[t4 + 1]; }
            } else if (t4 + 1 < nt4) {
#pragma unroll
                for (int u = 0; u < 4; ++u) {
                    xpn0[u] = xps0[(size_t)(t4 * 4 + 4 + u) * G4];
                    xpn1[u] = xps1[(size_t)(t4 * 4 + 4 + u) * G4];
                }
            }
#pragma unroll
            for (int u = 0; u < 4; ++u) {
                const int buf = u & 1;                 // static step parity
                // two independent chains: scheduler interleaves their stalls
                float s0 = dotred(w, hh + buf * 256 + 16 * j,       bp1, bp2, bp3);
                float s1 = dotred(w, hh + buf * 256 + HH + 16 * j,  bp1, bp2, bp3);
                float pre0, pre1;
                if (isA) {
                    float xt0 = (u == 0) ? xq0.x : (u == 1) ? xq0.y
                              : (u == 2) ? xq0.z : xq0.w;
                    float xt1 = (u == 0) ? xq1.x : (u == 1) ? xq1.y
                              : (u == 2) ? xq1.z : xq1.w;
                    pre0 = fmaf(xt0, wih_l, s0 + bias_l);
                    pre1 = fmaf(xt1, wih_l, s1 + bias_l);
                } else {
                    pre0 = s0 + xpc0[u];
                    pre1 = s1 + xpc1[u];
                }
                // one activation per lane per batch
                float e0  = __expf(pre0 * fe);
                float e1  = __expf(pre1 * fe);
                float r0 = __builtin_amdgcn_rcpf(1.0f + e0);
                float r1 = __builtin_amdgcn_rcpf(1.0f + e1);
                float a0 = fmaf(fm, r0, fa);
                float a1 = fmaf(fm, r1, fa);
                // gather at gate-i owners: f@j^7, g@j^2, o@j^5
                float f0 = dpp_mov<0x141>(a0);
                float f1 = dpp_mov<0x141>(a1);
                float g0 = dpp_mov<0x4E>(a0);
                float g1 = dpp_mov<0x4E>(a1);
                float o0 = dpp_mov<0x4E>(f0);
                float o1 = dpp_mov<0x4E>(f1);
                cr0 = fmaf(f0, cr0, a0 * g0);          // c = f*c + i*g
                cr1 = fmaf(f1, cr1, a1 * g1);
                float th0 = tanh_f(cr0);
                float th1 = tanh_f(cr1);
                float hv0 = o0 * th0;                  // h = o*tanh(c)
                float hv1 = o1 * th1;
                hf0 = hv0; hf1 = hv1;
                if (owner) {
                    hh[(buf ^ 1) * 256 + myc]      = (_Float16)hv0;
                    hh[(buf ^ 1) * 256 + HH + myc] = (_Float16)hv1;
                    if (isA) {
                        ring0[(size_t)(t4 * 4 + u) * HH + myc] = (_Float16)hv0;
                        ring1[(size_t)(t4 * 4 + u) * HH + myc] = (_Float16)hv1;
                    } else {
                        pa0 += (double)hv0;
                        pa1 += (double)hv1;
                    }
                }
                __syncthreads();
            }
            xq0 = xn0; xq1 = xn1;
            if (!isA) {
#pragma unroll
                for (int u = 0; u < 4; ++u) { xpc0[u] = xpn0[u]; xpc1[u] = xpn1[u]; }
            }
        }
        if (owner) {
            cst[b0 * HH + myc] = cr0;
            cst[b1 * HH + myc] = cr1;
            hst[b0 * HH + myc] = hf0;
            hst[b1 * HH + myc] = hf1;
            if (!isA) {
                pooled[b0 * HH + myc] += pa0;
                pooled[b1 * HH + myc] += pa1;
            }
        }

    } else {
        // ---------------- stage B: xp1 = Wih1 @ h1 + bias, chunk c-1 -------
        const int bc = c - 1;
        if (bc < 0 || bc >= nchunks) return;
        const int ib = blockIdx.x - 8;        // 0..63
        const int bb = ib >> 3;               // batch
        const int sl = ib & 7;                // t-slice (stride 8)
        v2h w[8][8];
        load_w8h(Wih1, Q, j, w);
        const float bias_l = bih1[myrow] + bhh1[myrow];
        const _Float16* hrp = h1ring
            + ((size_t)((bc & 1) * BB + bb)) * (size_t)chunkT * HH;
        float* xpw = xpring + ((size_t)((bc & 1) * BB + bb)) * (size_t)chunkT * G4;
        if (t < HH) hh[t] = hrp[(size_t)sl * HH + t];
        __syncthreads();
        int pb = 0;
        for (int tt = sl; tt < chunkT; tt += 8) {
            int ttn = tt + 8;
            bool pf = (t < HH) && (ttn < chunkT);
            _Float16 hn = (_Float16)0.f;
            if (pf) hn = hrp[(size_t)ttn * HH + t];          // prefetch
            float sfin = dotred(w, hh + pb * HH + 16 * j, bp1, bp2, bp3);
            if (pf) hh[(pb ^ 1) * HH + t] = hn;
            xpw[(size_t)tt * G4 + 4 * myc + gatej] = sfin + bias_l;
            __syncthreads();
            pb ^= 1;
        }
    }
}

// ---------------- head: mean-pool (done) -> FC+ReLU -> FC ------------------
__global__ void head_kernel(const double* __restrict__ pooled,
                            const float* __restrict__ fcW1, const float* __restrict__ fcb1,
                            const float* __restrict__ fcW2, const float* __restrict__ fcb2,
                            float* __restrict__ out)
{
    __shared__ float p_s[HH];
    __shared__ float hid_s[64];
    const int b = blockIdx.x, t = threadIdx.x;
    if (t < HH) p_s[t] = (float)(pooled[b * HH + t] * (1.0 / (double)TT));
    __syncthreads();
    if (t < 64) {
        float acc = fcb1[t];
#pragma unroll 8
        for (int k = 0; k < HH; ++k) acc = fmaf(p_s[k], fcW1[t * HH + k], acc);
        hid_s[t] = fmaxf(acc, 0.f);
    }
    __syncthreads();
    if (t < 11) {
        float acc = fcb2[t];
#pragma unroll
        for (int k = 0; k < 64; ++k) acc = fmaf(hid_s[k], fcW2[t * 64 + k], acc);
        out[b * 11 + t] = acc;
    }
}

// ---------------------------------------------------------------------------
extern "C" void kernel_launch(void* const* d_in, const int* in_sizes, int n_in,
                              void* d_out, int out_size, void* d_ws, size_t ws_size,
                              hipStream_t stream)
{
    const float* x    = (const float*)d_in[0];
    const float* Wih0 = (const float*)d_in[1];
    const float* Whh0 = (const float*)d_in[2];
    const float* bih0 = (const float*)d_in[3];
    const float* bhh0 = (const float*)d_in[4];
    const float* Wih1 = (const float*)d_in[5];
    const float* Whh1 = (const float*)d_in[6];
    const float* bih1 = (const float*)d_in[7];
    const float* bhh1 = (const float*)d_in[8];
    const float* fcW1 = (const float*)d_in[9];
    const float* fcb1 = (const float*)d_in[10];
    const float* fcW2 = (const float*)d_in[11];
    const float* fcb2 = (const float*)d_in[12];
    float* out = (float*)d_out;

    // ---- workspace layout ----
    char* wsp = (char*)d_ws;
    float*  h1s    = (float*) (wsp + 0);
    float*  c1s    = (float*) (wsp + 4096);
    float*  h2s    = (float*) (wsp + 8192);
    float*  c2s    = (float*) (wsp + 12288);
    double* pooled = (double*)(wsp + 16384);          // 8 KB
    const size_t STATE_BYTES = 24576;

    // per-t ring bytes: h1 fp16 2*8*128*2 = 4096 ; xp fp32 2*8*512*4 = 32768
    static const int cands[] = {3200, 1600, 800, 400, 160, 80, 40, 8};
    int chunkT = 8;
    for (int i = 0; i < 8; ++i) {
        size_t need = STATE_BYTES + (size_t)36864 * (size_t)cands[i];
        if (need <= ws_size) { chunkT = cands[i]; break; }
    }
    const int nchunks = TT / chunkT;

    _Float16* h1ring = (_Float16*)(wsp + STATE_BYTES);
    float* xpring = (float*)(wsp + STATE_BYTES + (size_t)2 * BB * chunkT * HH * 2);

    // zero persistent state (h/c/pooled); ws is re-poisoned before every call
    hipMemsetAsync(d_ws, 0, STATE_BYTES, stream);

    // pipeline: slot c runs A(c) || B(c-1) || C(c-2)
    const int nslots = nchunks + 2;
    for (int c = 0; c < nslots; ++c) {
        lstm_slot_kernel<<<72, 512, 0, stream>>>(
            x, Wih0, Whh0, bih0, bhh0, Wih1, Whh1, bih1, bhh1,
            h1s, c1s, h2s, c2s, pooled, h1ring, xpring,
            c, chunkT, nchunks);
    }
    head_kernel<<<BB, 128, 0, stream>>>(pooled, fcW1, fcb1, fcW2, fcb2, out);
}

// Round 11
// 58324.530 us; speedup vs baseline: 2.1794x; 1.9763x over previous
//
#include <hip/hip_runtime.h>

#define HH 128      // hidden size
#define G4 512      // 4*HH gates
#define TT 102400   // sequence length
#define BB 8        // batch

typedef _Float16 v2h __attribute__((ext_vector_type(2)));

#if __has_builtin(__builtin_amdgcn_fdot2)
#define FDOT2(a, b, c) __builtin_amdgcn_fdot2((a), (b), (c), false)
#else
static __device__ __forceinline__ float fdot2_fb(v2h a, v2h b, float c) {
    return fmaf((float)a[0], (float)b[0], fmaf((float)a[1], (float)b[1], c));
}
#define FDOT2(a, b, c) fdot2_fb((a), (b), (c))
#endif

// DPP lane move (VALU pipe): 0xB1=xor1(quad), 0x4E=xor2(quad), 0x141=xor7(row-half mirror)
template<int CTRL>
__device__ __forceinline__ float dpp_mov(float v) {
    return __int_as_float(
        __builtin_amdgcn_update_dpp(0, __float_as_int(v), CTRL, 0xF, 0xF, true));
}

__device__ __forceinline__ float tanh_f(float x) {
    return fmaf(2.0f, __builtin_amdgcn_rcpf(1.0f + __expf(-2.0f * x)), -1.0f);
}

union HI { int i; v2h h; };

// ---------------------------------------------------------------------------
// R7-verified reduce-to-distinct: lane j of each 8-lane group covers
// k in [16j,16j+16) of 8 gate rows (rho: bit0=cell, bits2:1=gate).
// Keep-functionals (GF(2)): phi1=j0^j2 (mask1), phi2=j0^j1 (mask2), phi3=j2
// (mask7). Lane j ends with the FULL 128-dot of row
// (cell=j0^j2, gate=2*(j0^j1)+j2). cell0 {i@0,f@7,g@2,o@5}, cell1 {i@3,f@4,g@1,o@6}.
// ---------------------------------------------------------------------------
__device__ __forceinline__ float dotred(const v2h w[8][8],
                                        const _Float16* __restrict__ hsl,
                                        bool bp1, bool bp2, bool bp3) {
    const int4* hp4 = (const int4*)hsl;     // 2x ds_read_b128 (16 halfs)
    int4 ha = hp4[0], hb = hp4[1];
    int hp[8] = {ha.x, ha.y, ha.z, ha.w, hb.x, hb.y, hb.z, hb.w};
    float acc[8];
#pragma unroll
    for (int r = 0; r < 8; ++r) acc[r] = 0.f;
#pragma unroll
    for (int i = 0; i < 8; ++i) {
        HI u; u.i = hp[i];
#pragma unroll
        for (int r = 0; r < 8; ++r) acc[r] = FDOT2(w[r][i], u.h, acc[r]);
    }
    // round 1 (mask 1): reduce cell bit; keep rho0 == bp1
    float b0[4];
#pragma unroll
    for (int m = 0; m < 4; ++m) {
        float send = bp1 ? acc[2 * m] : acc[2 * m + 1];
        float keep = bp1 ? acc[2 * m + 1] : acc[2 * m];
        b0[m] = keep + dpp_mov<0xB1>(send);
    }
    // round 2 (mask 2): reduce gate-hi bit; keep g1 == bp2 (= j0^j1)
    float d0[2];
#pragma unroll
    for (int i = 0; i < 2; ++i) {
        float send = bp2 ? b0[i] : b0[i + 2];
        float keep = bp2 ? b0[i + 2] : b0[i];
        d0[i] = keep + dpp_mov<0x4E>(send);
    }
    // round 3 (mask 7): reduce gate-lo bit; keep g0 == bp3 (= j2)
    float send = bp3 ? d0[0] : d0[1];
    float keep = bp3 ? d0[1] : d0[0];
    return keep + dpp_mov<0x141>(send);
}

// load this lane's fp16 weight slices: rows rho=0..7 -> W row 2Q+(rho&1)+128*(rho>>1)
__device__ __forceinline__ void load_w8h(const float* __restrict__ W,
                                         int Q, int j, v2h w[8][8]) {
#pragma unroll
    for (int r = 0; r < 8; ++r) {
        int row = 2 * Q + (r & 1) + 128 * (r >> 1);
        const float4* rp = (const float4*)(W + (size_t)row * HH + 16 * j);
#pragma unroll
        for (int i = 0; i < 4; ++i) {
            float4 f = rp[i];
            w[r][2 * i]     = (v2h){(_Float16)f.x, (_Float16)f.y};
            w[r][2 * i + 1] = (v2h){(_Float16)f.z, (_Float16)f.w};
        }
    }
}

// ---------------------------------------------------------------------------
// One pipeline slot (512 threads/block) — R7-verified structure:
//   blocks 0..7  = stage A (layer0 chain, chunk c)
//   blocks 8..15 = stage C (layer1 chain, chunk c-2)
//   blocks 16..79= stage B (xp1 GEMM, chunk c-1): 8 batch x 8 t-slice
// Stages independent within a launch; stream order gives producer->consumer
// ordering across launches. Chain CUs are VALU-issue-bound (R10 diagnostic):
// per-step floor ~577ns in this family — do not add per-CU issue.
// ---------------------------------------------------------------------------
__global__ void __launch_bounds__(512, 2)
lstm_slot_kernel(
    const float* __restrict__ x,
    const float* __restrict__ Wih0, const float* __restrict__ Whh0,
    const float* __restrict__ bih0, const float* __restrict__ bhh0,
    const float* __restrict__ Wih1, const float* __restrict__ Whh1,
    const float* __restrict__ bih1, const float* __restrict__ bhh1,
    float* __restrict__ h1s, float* __restrict__ c1s,
    float* __restrict__ h2s, float* __restrict__ c2s,
    double* __restrict__ pooled,
    _Float16* __restrict__ h1ring,  // [2][B][chunkT][HH]   fp16
    float* __restrict__ xpring,     // [2][B][chunkT][HH][4] (t,cell,gate) fp32
    int c, int chunkT, int nchunks)
{
    __shared__ __align__(32) _Float16 hh[2 * HH];
    const int t = threadIdx.x;
    const int Q = t >> 3;                 // 8-lane group -> cells {2Q, 2Q+1}
    const int j = t & 7;
    const bool bp1 = ((j ^ (j >> 2)) & 1) != 0;   // phi1 = j0^j2 (cell bit)
    const bool bp2 = ((j ^ (j >> 1)) & 1) != 0;   // phi2 = j0^j1 (gate hi)
    const bool bp3 = ((j >> 2) & 1) != 0;         // phi3 = j2    (gate lo)
    const int cellj = bp1 ? 1 : 0;
    const int gatej = (bp2 ? 2 : 0) + (bp3 ? 1 : 0);
    const int myc   = 2 * Q + cellj;
    const int myrow = myc + 128 * gatej;
    const bool owner = (gatej == 0);              // gate-i lanes: j in {0,3}
    // branchless activation constants: sigmoid for i,f,o; tanh for g(=gate2)
    const bool isg = (gatej == 2);
    const float fe = isg ? -2.f : -1.f;
    const float fm = isg ?  2.f :  1.f;
    const float fa = isg ? -1.f :  0.f;

    if (blockIdx.x < 16) {
        // =============== chain stages (A: layer0, C: layer1) ===============
        const bool isA = (blockIdx.x < 8);
        const int cc = isA ? c : (c - 2);
        if (cc < 0 || cc >= nchunks) return;
        const int b = blockIdx.x & 7;

        v2h w[8][8];
        load_w8h(isA ? Whh0 : Whh1, Q, j, w);
        float bias_l = 0.f, wih_l = 0.f;
        if (isA) { bias_l = bih0[myrow] + bhh0[myrow]; wih_l = Wih0[myrow]; }

        float* hst = isA ? h1s : h2s;
        float* cst = isA ? c1s : c2s;
        float c_reg = cst[b * HH + myc];
        if (t < HH) hh[t] = (_Float16)hst[b * HH + t];

        _Float16* ringp = h1ring + ((size_t)((c & 1) * BB + b)) * (size_t)chunkT * HH;
        const float4* xb4 = (const float4*)(x + (size_t)b * TT + (size_t)cc * chunkT);
        const float* xps = xpring
            + ((size_t)((cc & 1) * BB + b)) * (size_t)chunkT * G4 + 4 * myc + gatej;

        const int nt4 = chunkT >> 2;
        float4 xq = {0, 0, 0, 0};
        float xpc[4] = {0, 0, 0, 0};
        if (isA) xq = xb4[0];
        else {
#pragma unroll
            for (int u = 0; u < 4; ++u) xpc[u] = xps[(size_t)u * G4];
        }
        double pacc = 0.0;
        float hfin = 0.f;
        __syncthreads();

        for (int t4 = 0; t4 < nt4; ++t4) {
            float4 xqn = {0, 0, 0, 0};
            float xpn[4] = {0, 0, 0, 0};
            if (isA) {
                if (t4 + 1 < nt4) xqn = xb4[t4 + 1];
            } else if (t4 + 1 < nt4) {
#pragma unroll
                for (int u = 0; u < 4; ++u)
                    xpn[u] = xps[(size_t)(t4 * 4 + 4 + u) * G4];
            }
#pragma unroll
            for (int u = 0; u < 4; ++u) {
                const int buf = u & 1;                 // static step parity
                float sfin = dotred(w, hh + buf * HH + 16 * j, bp1, bp2, bp3);
                float pre;
                if (isA) {
                    float xt = (u == 0) ? xq.x : (u == 1) ? xq.y
                             : (u == 2) ? xq.z : xq.w;
                    pre = fmaf(xt, wih_l, sfin + bias_l);
                } else {
                    pre = sfin + xpc[u];
                }
                // one activation per lane (its own gate)
                float e  = __expf(pre * fe);
                float rr = __builtin_amdgcn_rcpf(1.0f + e);
                float act = fmaf(fm, rr, fa);
                // gate-gather at owners (gate i): f@j^7, g@j^2, o@j^5
                float t1 = dpp_mov<0x141>(act);   // act[j^7] = f
                float t2 = dpp_mov<0x4E>(act);    // act[j^2] = g
                float t3 = dpp_mov<0x4E>(t1);     // act[j^5] = o
                c_reg = fmaf(t1, c_reg, act * t2);   // c = f*c + i*g
                float th = tanh_f(c_reg);
                float hv = t3 * th;                  // h = o*tanh(c)
                hfin = hv;
                if (owner) {
                    hh[(buf ^ 1) * HH + myc] = (_Float16)hv;
                    if (isA) ringp[(size_t)(t4 * 4 + u) * HH + myc] = (_Float16)hv;
                    else     pacc += (double)hv;
                }
                __syncthreads();
            }
            xq = xqn;
            if (!isA) {
#pragma unroll
                for (int u = 0; u < 4; ++u) xpc[u] = xpn[u];
            }
        }
        if (owner) {
            cst[b * HH + myc] = c_reg;
            hst[b * HH + myc] = hfin;
            if (!isA) pooled[b * HH + myc] += pacc;
        }

    } else {
        // ---------------- stage B: xp1 = Wih1 @ h1 + bias, chunk c-1 -------
        const int bc = c - 1;
        if (bc < 0 || bc >= nchunks) return;
        const int ib = blockIdx.x - 16;       // 0..63
        const int bb = ib >> 3;               // batch
        const int sl = ib & 7;                // t-slice (stride 8)
        v2h w[8][8];
        load_w8h(Wih1, Q, j, w);
        const float bias_l = bih1[myrow] + bhh1[myrow];
        const _Float16* hrp = h1ring
            + ((size_t)((bc & 1) * BB + bb)) * (size_t)chunkT * HH;
        float* xpw = xpring + ((size_t)((bc & 1) * BB + bb)) * (size_t)chunkT * G4;
        if (t < HH) hh[t] = hrp[(size_t)sl * HH + t];
        __syncthreads();
        int pb = 0;
        for (int tt = sl; tt < chunkT; tt += 8) {
            int ttn = tt + 8;
            bool pf = (t < HH) && (ttn < chunkT);
            _Float16 hn = (_Float16)0.f;
            if (pf) hn = hrp[(size_t)ttn * HH + t];          // prefetch
            float sfin = dotred(w, hh + pb * HH + 16 * j, bp1, bp2, bp3);
            if (pf) hh[(pb ^ 1) * HH + t] = hn;
            xpw[(size_t)tt * G4 + 4 * myc + gatej] = sfin + bias_l;
            __syncthreads();
            pb ^= 1;
        }
    }
}

// ---------------- head: mean-pool (done) -> FC+ReLU -> FC ------------------
__global__ void head_kernel(const double* __restrict__ pooled,
                            const float* __restrict__ fcW1, const float* __restrict__ fcb1,
                            const float* __restrict__ fcW2, const float* __restrict__ fcb2,
                            float* __restrict__ out)
{
    __shared__ float p_s[HH];
    __shared__ float hid_s[64];
    const int b = blockIdx.x, t = threadIdx.x;
    if (t < HH) p_s[t] = (float)(pooled[b * HH + t] * (1.0 / (double)TT));
    __syncthreads();
    if (t < 64) {
        float acc = fcb1[t];
#pragma unroll 8
        for (int k = 0; k < HH; ++k) acc = fmaf(p_s[k], fcW1[t * HH + k], acc);
        hid_s[t] = fmaxf(acc, 0.f);
    }
    __syncthreads();
    if (t < 11) {
        float acc = fcb2[t];
#pragma unroll
        for (int k = 0; k < 64; ++k) acc = fmaf(hid_s[k], fcW2[t * 64 + k], acc);
        out[b * 11 + t] = acc;
    }
}

// ---------------------------------------------------------------------------
extern "C" void kernel_launch(void* const* d_in, const int* in_sizes, int n_in,
                              void* d_out, int out_size, void* d_ws, size_t ws_size,
                              hipStream_t stream)
{
    const float* x    = (const float*)d_in[0];
    const float* Wih0 = (const float*)d_in[1];
    const float* Whh0 = (const float*)d_in[2];
    const float* bih0 = (const float*)d_in[3];
    const float* bhh0 = (const float*)d_in[4];
    const float* Wih1 = (const float*)d_in[5];
    const float* Whh1 = (const float*)d_in[6];
    const float* bih1 = (const float*)d_in[7];
    const float* bhh1 = (const float*)d_in[8];
    const float* fcW1 = (const float*)d_in[9];
    const float* fcb1 = (const float*)d_in[10];
    const float* fcW2 = (const float*)d_in[11];
    const float* fcb2 = (const float*)d_in[12];
    float* out = (float*)d_out;

    // ---- workspace layout ----
    char* wsp = (char*)d_ws;
    float*  h1s    = (float*) (wsp + 0);
    float*  c1s    = (float*) (wsp + 4096);
    float*  h2s    = (float*) (wsp + 8192);
    float*  c2s    = (float*) (wsp + 12288);
    double* pooled = (double*)(wsp + 16384);          // 8 KB
    const size_t STATE_BYTES = 24576;

    // chunkT=1600 (vs 3200): pipeline fill/drain overhead (nchunks+2)/nchunks
    // drops 1.0625 -> 1.03; chain code identical. per-t ring bytes:
    // h1 fp16 2*8*128*2 = 4096 ; xp fp32 2*8*512*4 = 32768  => 36864
    static const int cands[] = {1600, 800, 400, 160, 80, 40, 8};
    int chunkT = 8;
    for (int i = 0; i < 7; ++i) {
        size_t need = STATE_BYTES + (size_t)36864 * (size_t)cands[i];
        if (need <= ws_size) { chunkT = cands[i]; break; }
    }
    const int nchunks = TT / chunkT;

    _Float16* h1ring = (_Float16*)(wsp + STATE_BYTES);
    float* xpring = (float*)(wsp + STATE_BYTES + (size_t)2 * BB * chunkT * HH * 2);

    // zero persistent state (h/c/pooled); ws is re-poisoned before every call
    hipMemsetAsync(d_ws, 0, STATE_BYTES, stream);

    // pipeline: slot c runs A(c) || B(c-1) || C(c-2)
    const int nslots = nchunks + 2;
    for (int c = 0; c < nslots; ++c) {
        lstm_slot_kernel<<<80, 512, 0, stream>>>(
            x, Wih0, Whh0, bih0, bhh0, Wih1, Whh1, bih1, bhh1,
            h1s, c1s, h2s, c2s, pooled, h1ring, xpring,
            c, chunkT, nchunks);
    }
    head_kernel<<<BB, 128, 0, stream>>>(pooled, fcW1, fcb1, fcW2, fcb2, out);
}

// Round 12
// 58022.363 us; speedup vs baseline: 2.1908x; 1.0052x over previous
//
#include <hip/hip_runtime.h>

#define HH 128      // hidden size
#define G4 512      // 4*HH gates
#define TT 102400   // sequence length
#define BB 8        // batch

typedef _Float16 v2h __attribute__((ext_vector_type(2)));

#if __has_builtin(__builtin_amdgcn_fdot2)
#define FDOT2(a, b, c) __builtin_amdgcn_fdot2((a), (b), (c), false)
#else
static __device__ __forceinline__ float fdot2_fb(v2h a, v2h b, float c) {
    return fmaf((float)a[0], (float)b[0], fmaf((float)a[1], (float)b[1], c));
}
#define FDOT2(a, b, c) fdot2_fb((a), (b), (c))
#endif

// DPP lane move (VALU pipe): 0xB1=xor1(quad), 0x4E=xor2(quad), 0x141=xor7(row-half mirror)
template<int CTRL>
__device__ __forceinline__ float dpp_mov(float v) {
    return __int_as_float(
        __builtin_amdgcn_update_dpp(0, __float_as_int(v), CTRL, 0xF, 0xF, true));
}

__device__ __forceinline__ float tanh_f(float x) {
    return fmaf(2.0f, __builtin_amdgcn_rcpf(1.0f + __expf(-2.0f * x)), -1.0f);
}

union HI { int i; v2h h; };

// ---------------------------------------------------------------------------
// R7-verified reduce-to-distinct: lane j of each 8-lane group covers
// k in [16j,16j+16) of 8 gate rows (rho: bit0=cell, bits2:1=gate).
// Keep-functionals (GF(2)): phi1=j0^j2 (mask1), phi2=j0^j1 (mask2), phi3=j2
// (mask7). Lane j ends with the FULL 128-dot of row
// (cell=j0^j2, gate=2*(j0^j1)+j2). cell0 {i@0,f@7,g@2,o@5}, cell1 {i@3,f@4,g@1,o@6}.
// ---------------------------------------------------------------------------
__device__ __forceinline__ float dotred(const v2h w[8][8],
                                        const _Float16* __restrict__ hsl,
                                        bool bp1, bool bp2, bool bp3) {
    const int4* hp4 = (const int4*)hsl;     // 2x ds_read_b128 (16 halfs)
    int4 ha = hp4[0], hb = hp4[1];
    int hp[8] = {ha.x, ha.y, ha.z, ha.w, hb.x, hb.y, hb.z, hb.w};
    float acc[8];
#pragma unroll
    for (int r = 0; r < 8; ++r) acc[r] = 0.f;
#pragma unroll
    for (int i = 0; i < 8; ++i) {
        HI u; u.i = hp[i];
#pragma unroll
        for (int r = 0; r < 8; ++r) acc[r] = FDOT2(w[r][i], u.h, acc[r]);
    }
    // round 1 (mask 1): reduce cell bit; keep rho0 == bp1
    float b0[4];
#pragma unroll
    for (int m = 0; m < 4; ++m) {
        float send = bp1 ? acc[2 * m] : acc[2 * m + 1];
        float keep = bp1 ? acc[2 * m + 1] : acc[2 * m];
        b0[m] = keep + dpp_mov<0xB1>(send);
    }
    // round 2 (mask 2): reduce gate-hi bit; keep g1 == bp2 (= j0^j1)
    float d0[2];
#pragma unroll
    for (int i = 0; i < 2; ++i) {
        float send = bp2 ? b0[i] : b0[i + 2];
        float keep = bp2 ? b0[i + 2] : b0[i];
        d0[i] = keep + dpp_mov<0x4E>(send);
    }
    // round 3 (mask 7): reduce gate-lo bit; keep g0 == bp3 (= j2)
    float send = bp3 ? d0[0] : d0[1];
    float keep = bp3 ? d0[1] : d0[0];
    return keep + dpp_mov<0x141>(send);
}

// load this lane's fp16 weight slices: rows rho=0..7 -> W row 2Q+(rho&1)+128*(rho>>1)
__device__ __forceinline__ void load_w8h(const float* __restrict__ W,
                                         int Q, int j, v2h w[8][8]) {
#pragma unroll
    for (int r = 0; r < 8; ++r) {
        int row = 2 * Q + (r & 1) + 128 * (r >> 1);
        const float4* rp = (const float4*)(W + (size_t)row * HH + 16 * j);
#pragma unroll
        for (int i = 0; i < 4; ++i) {
            float4 f = rp[i];
            w[r][2 * i]     = (v2h){(_Float16)f.x, (_Float16)f.y};
            w[r][2 * i + 1] = (v2h){(_Float16)f.z, (_Float16)f.w};
        }
    }
}

// ---------------------------------------------------------------------------
// One pipeline slot (512 threads/block) — R7/R11-verified structure:
//   blocks 0..7  = stage A (layer0 chain, chunk c)
//   blocks 8..15 = stage C (layer1 chain, chunk c-2)
//   blocks 16..79= stage B (xp1 GEMM, chunk c-1): 8 batch x 8 t-slice
// Stages independent within a launch; stream order gives producer->consumer
// ordering across launches. Chain CUs are VALU-issue-bound (R10 diagnostic):
// per-step floor ~550ns in this family — do not add per-CU issue.
// ---------------------------------------------------------------------------
__global__ void __launch_bounds__(512, 2)
lstm_slot_kernel(
    const float* __restrict__ x,
    const float* __restrict__ Wih0, const float* __restrict__ Whh0,
    const float* __restrict__ bih0, const float* __restrict__ bhh0,
    const float* __restrict__ Wih1, const float* __restrict__ Whh1,
    const float* __restrict__ bih1, const float* __restrict__ bhh1,
    float* __restrict__ h1s, float* __restrict__ c1s,
    float* __restrict__ h2s, float* __restrict__ c2s,
    double* __restrict__ pooled,
    _Float16* __restrict__ h1ring,  // [2][B][chunkT][HH]   fp16
    float* __restrict__ xpring,     // [2][B][chunkT][HH][4] (t,cell,gate) fp32
    int c, int chunkT, int nchunks)
{
    __shared__ __align__(32) _Float16 hh[2 * HH];
    const int t = threadIdx.x;
    const int Q = t >> 3;                 // 8-lane group -> cells {2Q, 2Q+1}
    const int j = t & 7;
    const bool bp1 = ((j ^ (j >> 2)) & 1) != 0;   // phi1 = j0^j2 (cell bit)
    const bool bp2 = ((j ^ (j >> 1)) & 1) != 0;   // phi2 = j0^j1 (gate hi)
    const bool bp3 = ((j >> 2) & 1) != 0;         // phi3 = j2    (gate lo)
    const int cellj = bp1 ? 1 : 0;
    const int gatej = (bp2 ? 2 : 0) + (bp3 ? 1 : 0);
    const int myc   = 2 * Q + cellj;
    const int myrow = myc + 128 * gatej;
    const bool owner = (gatej == 0);              // gate-i lanes: j in {0,3}
    // branchless activation constants: sigmoid for i,f,o; tanh for g(=gate2)
    const bool isg = (gatej == 2);
    const float fe = isg ? -2.f : -1.f;
    const float fm = isg ?  2.f :  1.f;
    const float fa = isg ? -1.f :  0.f;

    if (blockIdx.x < 16) {
        // =============== chain stages (A: layer0, C: layer1) ===============
        const bool isA = (blockIdx.x < 8);
        const int cc = isA ? c : (c - 2);
        if (cc < 0 || cc >= nchunks) return;
        const int b = blockIdx.x & 7;

        v2h w[8][8];
        load_w8h(isA ? Whh0 : Whh1, Q, j, w);
        float bias_l = 0.f, wih_l = 0.f;
        if (isA) { bias_l = bih0[myrow] + bhh0[myrow]; wih_l = Wih0[myrow]; }

        float* hst = isA ? h1s : h2s;
        float* cst = isA ? c1s : c2s;
        float c_reg = cst[b * HH + myc];
        if (t < HH) hh[t] = (_Float16)hst[b * HH + t];

        _Float16* ringp = h1ring + ((size_t)((c & 1) * BB + b)) * (size_t)chunkT * HH;
        const float4* xb4 = (const float4*)(x + (size_t)b * TT + (size_t)cc * chunkT);
        const float* xps = xpring
            + ((size_t)((cc & 1) * BB + b)) * (size_t)chunkT * G4 + 4 * myc + gatej;

        const int nt4 = chunkT >> 2;
        float4 xq = {0, 0, 0, 0};
        float xpc[4] = {0, 0, 0, 0};
        if (isA) xq = xb4[0];
        else {
#pragma unroll
            for (int u = 0; u < 4; ++u) xpc[u] = xps[(size_t)u * G4];
        }
        double pacc = 0.0;
        float hfin = 0.f;
        __syncthreads();

        for (int t4 = 0; t4 < nt4; ++t4) {
            float4 xqn = {0, 0, 0, 0};
            float xpn[4] = {0, 0, 0, 0};
            if (isA) {
                if (t4 + 1 < nt4) xqn = xb4[t4 + 1];
            } else if (t4 + 1 < nt4) {
#pragma unroll
                for (int u = 0; u < 4; ++u)
                    xpn[u] = xps[(size_t)(t4 * 4 + 4 + u) * G4];
            }
#pragma unroll
            for (int u = 0; u < 4; ++u) {
                const int buf = u & 1;                 // static step parity
                float sfin = dotred(w, hh + buf * HH + 16 * j, bp1, bp2, bp3);
                float pre;
                if (isA) {
                    float xt = (u == 0) ? xq.x : (u == 1) ? xq.y
                             : (u == 2) ? xq.z : xq.w;
                    pre = fmaf(xt, wih_l, sfin + bias_l);
                } else {
                    pre = sfin + xpc[u];
                }
                // one activation per lane (its own gate)
                float e  = __expf(pre * fe);
                float rr = __builtin_amdgcn_rcpf(1.0f + e);
                float act = fmaf(fm, rr, fa);
                // gate-gather at owners (gate i): f@j^7, g@j^2, o@j^5
                float t1 = dpp_mov<0x141>(act);   // act[j^7] = f
                float t2 = dpp_mov<0x4E>(act);    // act[j^2] = g
                float t3 = dpp_mov<0x4E>(t1);     // act[j^5] = o
                c_reg = fmaf(t1, c_reg, act * t2);   // c = f*c + i*g
                float th = tanh_f(c_reg);
                float hv = t3 * th;                  // h = o*tanh(c)
                hfin = hv;
                if (owner) {
                    hh[(buf ^ 1) * HH + myc] = (_Float16)hv;
                    if (isA) ringp[(size_t)(t4 * 4 + u) * HH + myc] = (_Float16)hv;
                    else     pacc += (double)hv;
                }
                __syncthreads();
            }
            xq = xqn;
            if (!isA) {
#pragma unroll
                for (int u = 0; u < 4; ++u) xpc[u] = xpn[u];
            }
        }
        if (owner) {
            cst[b * HH + myc] = c_reg;
            hst[b * HH + myc] = hfin;
            if (!isA) pooled[b * HH + myc] += pacc;
        }

    } else {
        // ---------------- stage B: xp1 = Wih1 @ h1 + bias, chunk c-1 -------
        const int bc = c - 1;
        if (bc < 0 || bc >= nchunks) return;
        const int ib = blockIdx.x - 16;       // 0..63
        const int bb = ib >> 3;               // batch
        const int sl = ib & 7;                // t-slice (stride 8)
        v2h w[8][8];
        load_w8h(Wih1, Q, j, w);
        const float bias_l = bih1[myrow] + bhh1[myrow];
        const _Float16* hrp = h1ring
            + ((size_t)((bc & 1) * BB + bb)) * (size_t)chunkT * HH;
        float* xpw = xpring + ((size_t)((bc & 1) * BB + bb)) * (size_t)chunkT * G4;
        if (t < HH) hh[t] = hrp[(size_t)sl * HH + t];
        __syncthreads();
        int pb = 0;
        for (int tt = sl; tt < chunkT; tt += 8) {
            int ttn = tt + 8;
            bool pf = (t < HH) && (ttn < chunkT);
            _Float16 hn = (_Float16)0.f;
            if (pf) hn = hrp[(size_t)ttn * HH + t];          // prefetch
            float sfin = dotred(w, hh + pb * HH + 16 * j, bp1, bp2, bp3);
            if (pf) hh[(pb ^ 1) * HH + t] = hn;
            xpw[(size_t)tt * G4 + 4 * myc + gatej] = sfin + bias_l;
            __syncthreads();
            pb ^= 1;
        }
    }
}

// ---------------- head: mean-pool (done) -> FC+ReLU -> FC ------------------
__global__ void head_kernel(const double* __restrict__ pooled,
                            const float* __restrict__ fcW1, const float* __restrict__ fcb1,
                            const float* __restrict__ fcW2, const float* __restrict__ fcb2,
                            float* __restrict__ out)
{
    __shared__ float p_s[HH];
    __shared__ float hid_s[64];
    const int b = blockIdx.x, t = threadIdx.x;
    if (t < HH) p_s[t] = (float)(pooled[b * HH + t] * (1.0 / (double)TT));
    __syncthreads();
    if (t < 64) {
        float acc = fcb1[t];
#pragma unroll 8
        for (int k = 0; k < HH; ++k) acc = fmaf(p_s[k], fcW1[t * HH + k], acc);
        hid_s[t] = fmaxf(acc, 0.f);
    }
    __syncthreads();
    if (t < 11) {
        float acc = fcb2[t];
#pragma unroll
        for (int k = 0; k < 64; ++k) acc = fmaf(hid_s[k], fcW2[t * 64 + k], acc);
        out[b * 11 + t] = acc;
    }
}

// ---------------------------------------------------------------------------
extern "C" void kernel_launch(void* const* d_in, const int* in_sizes, int n_in,
                              void* d_out, int out_size, void* d_ws, size_t ws_size,
                              hipStream_t stream)
{
    const float* x    = (const float*)d_in[0];
    const float* Wih0 = (const float*)d_in[1];
    const float* Whh0 = (const float*)d_in[2];
    const float* bih0 = (const float*)d_in[3];
    const float* bhh0 = (const float*)d_in[4];
    const float* Wih1 = (const float*)d_in[5];
    const float* Whh1 = (const float*)d_in[6];
    const float* bih1 = (const float*)d_in[7];
    const float* bhh1 = (const float*)d_in[8];
    const float* fcW1 = (const float*)d_in[9];
    const float* fcb1 = (const float*)d_in[10];
    const float* fcW2 = (const float*)d_in[11];
    const float* fcb2 = (const float*)d_in[12];
    float* out = (float*)d_out;

    // ---- workspace layout ----
    char* wsp = (char*)d_ws;
    float*  h1s    = (float*) (wsp + 0);
    float*  c1s    = (float*) (wsp + 4096);
    float*  h2s    = (float*) (wsp + 8192);
    float*  c2s    = (float*) (wsp + 12288);
    double* pooled = (double*)(wsp + 16384);          // 8 KB
    const size_t STATE_BYTES = 24576;

    // chunkT=800 (vs 1600): fill factor 130/128=1.016 (was 1.031); rings
    // shrink to ~14.7MB (L2-resident, 32MB aggregate). R11 showed chunk
    // shrink beats its fill arithmetic via cache residency — one more notch.
    // per-t ring bytes: h1 fp16 4096 + xp fp32 32768 = 36864
    static const int cands[] = {800, 400, 160, 80, 40, 8};
    int chunkT = 8;
    for (int i = 0; i < 6; ++i) {
        size_t need = STATE_BYTES + (size_t)36864 * (size_t)cands[i];
        if (need <= ws_size) { chunkT = cands[i]; break; }
    }
    const int nchunks = TT / chunkT;

    _Float16* h1ring = (_Float16*)(wsp + STATE_BYTES);
    float* xpring = (float*)(wsp + STATE_BYTES + (size_t)2 * BB * chunkT * HH * 2);

    // zero persistent state (h/c/pooled); ws is re-poisoned before every call
    hipMemsetAsync(d_ws, 0, STATE_BYTES, stream);

    // pipeline: slot c runs A(c) || B(c-1) || C(c-2)
    const int nslots = nchunks + 2;
    for (int c = 0; c < nslots; ++c) {
        lstm_slot_kernel<<<80, 512, 0, stream>>>(
            x, Wih0, Whh0, bih0, bhh0, Wih1, Whh1, bih1, bhh1,
            h1s, c1s, h2s, c2s, pooled, h1ring, xpring,
            c, chunkT, nchunks);
    }
    head_kernel<<<BB, 128, 0, stream>>>(pooled, fcW1, fcb1, fcW2, fcb2, out);
}